// Round 8
// baseline (400.077 us; speedup 1.0000x reference)
//
#include <hip/hip_runtime.h>
#include <stdint.h>

#define EPSQ 1e-8f

typedef __attribute__((ext_vector_type(4))) int i32x4;

// ---- monotone float<->uint encoding so atomicMax(unsigned) orders floats ----
__device__ __forceinline__ unsigned enc_f(float f) {
    unsigned u = __float_as_uint(f);
    return (u & 0x80000000u) ? ~u : (u | 0x80000000u);
}
__device__ __forceinline__ float dec_f(unsigned u) {
    return (u & 0x80000000u) ? __uint_as_float(u & 0x7fffffffu)
                             : __uint_as_float(~u);
}

__device__ __forceinline__ float wave_max_f(float v) {
    #pragma unroll
    for (int off = 32; off; off >>= 1) v = fmaxf(v, __shfl_xor(v, off));
    return v;
}
__device__ __forceinline__ int wave_sum_i(int v) {
    #pragma unroll
    for (int off = 32; off; off >>= 1) v += __shfl_xor(v, off);
    return v;
}

// ---------------- fused prep: x partial max + per-row quant of w1, w2 -------
__global__ __launch_bounds__(256) void k_prep(
    const float4* __restrict__ x, long n4x, float* __restrict__ partials,
    const float* __restrict__ w1, signed char* __restrict__ w1q,
    float* __restrict__ sw1, int* __restrict__ rs1,
    const float* __restrict__ w2, signed char* __restrict__ w2q,
    float* __restrict__ sw2, int* __restrict__ rs2) {
    __shared__ float sm[4];
    __shared__ int   si[4];
    int b = blockIdx.x;
    int wid = threadIdx.x >> 6;
    if (b < 2048) {
        long i = (long)b * 256 + threadIdx.x;
        float m = -3.4e38f;
        for (; i < n4x; i += 2048L * 256) {
            float4 v = x[i];
            m = fmaxf(fmaxf(m, fmaxf(v.x, v.y)), fmaxf(v.z, v.w));
        }
        m = wave_max_f(m);
        if ((threadIdx.x & 63) == 0) sm[wid] = m;
        __syncthreads();
        if (threadIdx.x == 0)
            partials[b] = fmaxf(fmaxf(sm[0], sm[1]), fmaxf(sm[2], sm[3]));
        return;
    }
    const float* w; signed char* q; float* s_out; int* rs_out; int row, L;
    if (b < 2048 + 4096) { row = b - 2048; w = w1; q = w1q; s_out = sw1; rs_out = rs1; L = 1024; }
    else                 { row = b - 6144; w = w2; q = w2q; s_out = sw2; rs_out = rs2; L = 4096; }

    const float4* wr = (const float4*)(w + (long)row * L);
    int n4 = L >> 2;
    float m = 0.0f;
    for (int i = threadIdx.x; i < n4; i += 256) {
        float4 v = wr[i];
        m = fmaxf(m, fmaxf(fmaxf(fabsf(v.x), fabsf(v.y)),
                           fmaxf(fabsf(v.z), fabsf(v.w))));
    }
    m = wave_max_f(m);
    if ((threadIdx.x & 63) == 0) sm[wid] = m;
    __syncthreads();
    m = fmaxf(fmaxf(sm[0], sm[1]), fmaxf(sm[2], sm[3]));
    float s = fmaxf(m, EPSQ) / 127.0f;   // same fp32 ops as reference

    char4* qr = (char4*)(q + (long)row * L);
    int isum = 0;
    for (int i = threadIdx.x; i < n4; i += 256) {
        float4 v = wr[i];
        int a = min(max((int)rintf(v.x / s), -128), 127);
        int bb = min(max((int)rintf(v.y / s), -128), 127);
        int c = min(max((int)rintf(v.z / s), -128), 127);
        int d = min(max((int)rintf(v.w / s), -128), 127);
        isum += a + bb + c + d;
        char4 cc; cc.x = (char)a; cc.y = (char)bb; cc.z = (char)c; cc.w = (char)d;
        qr[i] = cc;
    }
    isum = wave_sum_i(isum);
    if ((threadIdx.x & 63) == 0) si[wid] = isum;
    __syncthreads();
    if (threadIdx.x == 0) {
        s_out[row]  = s;
        rs_out[row] = si[0] + si[1] + si[2] + si[3];
    }
}

// ---------------- 1-block reducer: max(partials[0..n)) -> encoded slot ------
__global__ __launch_bounds__(256) void k_reduce_max(const float* __restrict__ partials,
                                                    int n, unsigned* __restrict__ slot) {
    __shared__ float sm[4];
    float m = -3.4e38f;
    for (int i = threadIdx.x; i < n; i += 256) m = fmaxf(m, partials[i]);
    m = wave_max_f(m);
    if ((threadIdx.x & 63) == 0) sm[threadIdx.x >> 6] = m;
    __syncthreads();
    if (threadIdx.x == 0)
        *slot = enc_f(fmaxf(fmaxf(sm[0], sm[1]), fmaxf(sm[2], sm[3])));
}

// ---------------- activation quant x -> int8 (offset -128) ----------------
__global__ __launch_bounds__(256) void k_quant_act(const float4* __restrict__ in,
                                                   char4* __restrict__ out, long n4,
                                                   const unsigned* __restrict__ slot) {
    float s = fmaxf(dec_f(*slot), EPSQ) / 255.0f;
    long i = (long)blockIdx.x * 256 + threadIdx.x;
    for (; i < n4; i += (long)gridDim.x * 256) {
        float4 v = in[i];
        int a = min(max((int)rintf(v.x / s), 0), 255) - 128;
        int b = min(max((int)rintf(v.y / s), 0), 255) - 128;
        int c = min(max((int)rintf(v.z / s), 0), 255) - 128;
        int d = min(max((int)rintf(v.w / s), 0), 255) - 128;
        char4 cc; cc.x = (char)a; cc.y = (char)b; cc.z = (char)c; cc.w = (char)d;
        out[i] = cc;
    }
}

// ---------------- async global -> LDS, 16B per lane ----------------
__device__ __forceinline__ void gl_lds16(const signed char* g, signed char* l) {
    __builtin_amdgcn_global_load_lds(
        (const __attribute__((address_space(1))) unsigned int*)g,
        (__attribute__((address_space(3))) unsigned int*)l, 16, 0, 0);
}

// ---------------- i8 GEMM, 16x16x64 MFMA, 128x128 tile, BK=128 --------------
// A: LDS double-buffered (2 x 16KB), R4-proven 16-row-panel layout, staged with
//    4 gl_lds16/thread; drain (vmcnt(0)) happens one FULL compute phase after
//    issue -> staging latency hidden. One barrier per iter.
// B: NO LDS. Fragments are 16B/lane contiguous in K-major B -> direct
//    global_load_dwordx4 to VGPR. Dest-VGPR loads are compiler-pipelined with
//    fine-grained vmcnt (AITER-style MFMA<->load overlap); B is L1/L2-hot
//    (per-iter block footprint 16KB; whole w is 4MB).
// MODE 0: fp32 store; MODE 1: relu->global max only; MODE 2: relu->u8 quant store.
template<int MODE>
__global__ __launch_bounds__(256, 3) void k_gemm_i8(
    const signed char* __restrict__ A,   // [M][K]
    const signed char* __restrict__ B,   // [N][K]
    const float* __restrict__ s_w,       // [N]
    const int* __restrict__ rowsum,      // [N]
    const float* __restrict__ bias,      // [N]
    const unsigned* __restrict__ act_slot,
    float* __restrict__ Cf,              // MODE 0
    signed char* __restrict__ Cq,        // MODE 2
    unsigned* __restrict__ omax_slot,    // MODE 1: target; MODE 2: source
    int M, int N, long K) {
    __shared__ __align__(16) signed char Als[2][16384];
    __shared__ float red[4];

    const int t    = threadIdx.x;
    const int lane = t & 63;
    const int w    = t >> 6;
    const int m0   = blockIdx.y * 128;
    const int n0   = blockIdx.x * 128;
    const int mr   = lane & 15;   // row-in-panel / C-D col-in-16
    const int qq   = lane >> 4;   // k-group / C-D row-quad

    // A staging: wave w stages panels 2w,2w+1 (R4-proven 64B-per-row chunks)
    const signed char* a0 = A + (long)(m0 + w * 32 + mr) * K + qq * 16;
    const int ad_off = w * 4096 + lane * 16;

    const int wrow = (w >> 1) * 64;
    const int wcol = (w & 1) * 64;
    const int a_base = (w >> 1) * 8192 + lane * 16;

    // B direct-load base: lane reads 16B at row (n0+wcol+j*16+mr), k qq*16
    const signed char* bbase = B + (long)(n0 + wcol + mr) * K + qq * 16;

    i32x4 acc[4][4];
    #pragma unroll
    for (int i = 0; i < 4; i++)
        #pragma unroll
        for (int j = 0; j < 4; j++) acc[i][j] = (i32x4){0, 0, 0, 0};

    auto stage_A = [&](signed char* buf, long k0) {
        gl_lds16(a0 + k0,               buf + ad_off);
        gl_lds16(a0 + k0 + 64,          buf + ad_off + 1024);
        gl_lds16(a0 + k0 + 16 * K,      buf + ad_off + 2048);
        gl_lds16(a0 + k0 + 16 * K + 64, buf + ad_off + 3072);
    };

    const int NIT = (int)(K >> 7);
    stage_A(Als[0], 0);

    for (int it = 0; it < NIT; ++it) {
        const int cur = it & 1;
        __builtin_amdgcn_s_waitcnt(0x0F70);   // vmcnt(0): A[cur] staging landed
                                              // (issued a full compute phase ago)
        __syncthreads();                      // all staged; prev readers of buf^1 done
        if (it + 1 < NIT)
            stage_A(Als[cur ^ 1], (long)(it + 1) * 128);  // drains NEXT iter

        // B fragments: direct global->VGPR (compiler pipelines with vmcnt(N))
        i32x4 bf[2][4];
        #pragma unroll
        for (int kk = 0; kk < 2; kk++)
            #pragma unroll
            for (int j = 0; j < 4; j++)
                bf[kk][j] = *(const i32x4*)(bbase + (long)j * 16 * K
                                            + (long)it * 128 + kk * 64);
        #pragma unroll
        for (int kk = 0; kk < 2; kk++) {
            i32x4 af[4];
            #pragma unroll
            for (int i = 0; i < 4; i++)
                af[i] = *(const i32x4*)(Als[cur] + a_base + i * 2048 + kk * 1024);
            #pragma unroll
            for (int i = 0; i < 4; i++)
                #pragma unroll
                for (int j = 0; j < 4; j++)
                    acc[i][j] = __builtin_amdgcn_mfma_i32_16x16x64_i8(
                        af[i], bf[kk][j], acc[i][j], 0, 0, 0);
        }
    }

    // ---- epilogue ----
    const float s_act = fmaxf(dec_f(*act_slot), EPSQ) / 255.0f;

    if (MODE == 1) {
        // max(relu(h)); h = ssc*(v+bint) monotone in integer v per column
        float lmax = 0.0f;
        #pragma unroll
        for (int j = 0; j < 4; j++) {
            int im = -2147483647 - 1;
            #pragma unroll
            for (int i = 0; i < 4; i++)
                #pragma unroll
                for (int r = 0; r < 4; r++) im = max(im, acc[i][j][r]);
            int gn = n0 + wcol + j * 16 + mr;
            float ssc  = s_act * s_w[gn];
            float bint = rintf(bias[gn] / ssc);
            float h = ssc * ((float)(im + 128 * rowsum[gn]) + bint);
            lmax = fmaxf(lmax, h);
        }
        lmax = fmaxf(lmax, 0.0f);
        lmax = wave_max_f(lmax);
        if (lane == 0) red[w] = lmax;
        __syncthreads();
        if (t == 0)   // one atomic per block, staggered over the dispatch
            atomicMax(omax_slot,
                      enc_f(fmaxf(fmaxf(red[0], red[1]), fmaxf(red[2], red[3]))));
        return;
    }

    float s_oq = 1.0f;
    if (MODE == 2) s_oq = fmaxf(dec_f(*omax_slot), EPSQ) / 255.0f;

    #pragma unroll
    for (int j = 0; j < 4; j++) {
        int gn = n0 + wcol + j * 16 + mr;       // C/D col = lane&15
        float ssc  = s_act * s_w[gn];
        float bint = rintf(bias[gn] / ssc);
        int   icor = 128 * rowsum[gn];          // uint8 zero-point correction
        float fq   = (MODE == 2) ? (ssc / s_oq) : 0.0f;
        #pragma unroll
        for (int i = 0; i < 4; i++) {
            #pragma unroll
            for (int r = 0; r < 4; r++) {
                int gm = m0 + wrow + i * 16 + qq * 4 + r;  // C/D row
                float v = (float)(acc[i][j][r] + icor) + bint;
                if (MODE == 0) {
                    Cf[(long)gm * N + gn] = ssc * v;
                } else {
                    int qv = min(max((int)rintf(fq * v), 0), 255) - 128;
                    Cq[(long)gm * N + gn] = (signed char)qv;
                }
            }
        }
    }
}

extern "C" void kernel_launch(void* const* d_in, const int* in_sizes, int n_in,
                              void* d_out, int out_size, void* d_ws, size_t ws_size,
                              hipStream_t stream) {
    const float* x  = (const float*)d_in[0];  // [4,2048,1024]
    const float* w1 = (const float*)d_in[1];  // [4096,1024]
    const float* b1 = (const float*)d_in[2];  // [4096]
    const float* w2 = (const float*)d_in[3];  // [1024,4096]
    const float* b2 = (const float*)d_in[4];  // [1024]
    float* out = (float*)d_out;               // [4,2048,1024] fp32

    const int M = 8192, D = 1024, F = 4096;

    char* ws = (char*)d_ws;
    size_t off = 0;
    unsigned* slots = (unsigned*)ws;               off += 256;  // [0]=max x, [1]=max h
    float* partials = (float*)(ws + off);          off += 2048 * 4;
    signed char* xi  = (signed char*)(ws + off);   off += (size_t)M * D;  // 8 MB
    signed char* w1q = (signed char*)(ws + off);   off += (size_t)F * D;  // 4 MB
    signed char* w2q = (signed char*)(ws + off);   off += (size_t)D * F;  // 4 MB
    float* sw1 = (float*)(ws + off);               off += (size_t)F * 4;
    float* sw2 = (float*)(ws + off);               off += (size_t)D * 4;
    int* rs1   = (int*)(ws + off);                 off += (size_t)F * 4;
    int* rs2   = (int*)(ws + off);                 off += (size_t)D * 4;
    signed char* hq = (signed char*)(ws + off);    off += (size_t)M * F;  // 32 MB

    hipMemsetAsync(slots, 0, 8, stream);  // slots[1]=0 < any encoded real value

    k_prep<<<dim3(2048 + F + D), dim3(256), 0, stream>>>(
        (const float4*)x, (long)M * D / 4, partials,
        w1, w1q, sw1, rs1, w2, w2q, sw2, rs2);
    k_reduce_max<<<dim3(1), dim3(256), 0, stream>>>(partials, 2048, slots + 0);
    k_quant_act<<<dim3(2048), dim3(256), 0, stream>>>((const float4*)x, (char4*)xi,
                                                      (long)M * D / 4, slots + 0);
    // GEMM1 pass 1: max(relu(h)) only
    k_gemm_i8<1><<<dim3(F / 128, M / 128), dim3(256), 0, stream>>>(
        xi, w1q, sw1, rs1, b1, slots + 0, nullptr, nullptr, slots + 1, M, F, (long)D);
    // GEMM1 pass 2: write quantized h (int8, offset -128)
    k_gemm_i8<2><<<dim3(F / 128, M / 128), dim3(256), 0, stream>>>(
        xi, w1q, sw1, rs1, b1, slots + 0, nullptr, hq, slots + 1, M, F, (long)D);
    // GEMM2: fp32 output
    k_gemm_i8<0><<<dim3(D / 128, M / 128), dim3(256), 0, stream>>>(
        hq, w2q, sw2, rs2, b2, slots + 1, out, nullptr, nullptr, M, D, (long)F);

    (void)in_sizes; (void)n_in; (void)out_size; (void)ws_size;
}

// Round 9
// 324.378 us; speedup vs baseline: 1.2334x; 1.2334x over previous
//
#include <hip/hip_runtime.h>
#include <stdint.h>

#define EPSQ 1e-8f

typedef __attribute__((ext_vector_type(4))) int i32x4;

// ---- monotone float<->uint encoding so atomicMax(unsigned) orders floats ----
__device__ __forceinline__ unsigned enc_f(float f) {
    unsigned u = __float_as_uint(f);
    return (u & 0x80000000u) ? ~u : (u | 0x80000000u);
}
__device__ __forceinline__ float dec_f(unsigned u) {
    return (u & 0x80000000u) ? __uint_as_float(u & 0x7fffffffu)
                             : __uint_as_float(~u);
}

__device__ __forceinline__ float wave_max_f(float v) {
    #pragma unroll
    for (int off = 32; off; off >>= 1) v = fmaxf(v, __shfl_xor(v, off));
    return v;
}
__device__ __forceinline__ int wave_sum_i(int v) {
    #pragma unroll
    for (int off = 32; off; off >>= 1) v += __shfl_xor(v, off);
    return v;
}

// ---------------- fused prep: x partial max + per-row quant of w1, w2 -------
__global__ __launch_bounds__(256) void k_prep(
    const float4* __restrict__ x, long n4x, float* __restrict__ partials,
    const float* __restrict__ w1, signed char* __restrict__ w1q,
    float* __restrict__ sw1, int* __restrict__ rs1,
    const float* __restrict__ w2, signed char* __restrict__ w2q,
    float* __restrict__ sw2, int* __restrict__ rs2) {
    __shared__ float sm[4];
    __shared__ int   si[4];
    int b = blockIdx.x;
    int wid = threadIdx.x >> 6;
    if (b < 2048) {
        long i = (long)b * 256 + threadIdx.x;
        float m = -3.4e38f;
        for (; i < n4x; i += 2048L * 256) {
            float4 v = x[i];
            m = fmaxf(fmaxf(m, fmaxf(v.x, v.y)), fmaxf(v.z, v.w));
        }
        m = wave_max_f(m);
        if ((threadIdx.x & 63) == 0) sm[wid] = m;
        __syncthreads();
        if (threadIdx.x == 0)
            partials[b] = fmaxf(fmaxf(sm[0], sm[1]), fmaxf(sm[2], sm[3]));
        return;
    }
    const float* w; signed char* q; float* s_out; int* rs_out; int row, L;
    if (b < 2048 + 4096) { row = b - 2048; w = w1; q = w1q; s_out = sw1; rs_out = rs1; L = 1024; }
    else                 { row = b - 6144; w = w2; q = w2q; s_out = sw2; rs_out = rs2; L = 4096; }

    const float4* wr = (const float4*)(w + (long)row * L);
    int n4 = L >> 2;
    float m = 0.0f;
    for (int i = threadIdx.x; i < n4; i += 256) {
        float4 v = wr[i];
        m = fmaxf(m, fmaxf(fmaxf(fabsf(v.x), fabsf(v.y)),
                           fmaxf(fabsf(v.z), fabsf(v.w))));
    }
    m = wave_max_f(m);
    if ((threadIdx.x & 63) == 0) sm[wid] = m;
    __syncthreads();
    m = fmaxf(fmaxf(sm[0], sm[1]), fmaxf(sm[2], sm[3]));
    float s = fmaxf(m, EPSQ) / 127.0f;   // same fp32 ops as reference

    char4* qr = (char4*)(q + (long)row * L);
    int isum = 0;
    for (int i = threadIdx.x; i < n4; i += 256) {
        float4 v = wr[i];
        int a = min(max((int)rintf(v.x / s), -128), 127);
        int bb = min(max((int)rintf(v.y / s), -128), 127);
        int c = min(max((int)rintf(v.z / s), -128), 127);
        int d = min(max((int)rintf(v.w / s), -128), 127);
        isum += a + bb + c + d;
        char4 cc; cc.x = (char)a; cc.y = (char)bb; cc.z = (char)c; cc.w = (char)d;
        qr[i] = cc;
    }
    isum = wave_sum_i(isum);
    if ((threadIdx.x & 63) == 0) si[wid] = isum;
    __syncthreads();
    if (threadIdx.x == 0) {
        s_out[row]  = s;
        rs_out[row] = si[0] + si[1] + si[2] + si[3];
    }
}

// ---------------- 1-block reducer: max(partials[0..n)) -> encoded slot ------
__global__ __launch_bounds__(256) void k_reduce_max(const float* __restrict__ partials,
                                                    int n, unsigned* __restrict__ slot) {
    __shared__ float sm[4];
    float m = -3.4e38f;
    for (int i = threadIdx.x; i < n; i += 256) m = fmaxf(m, partials[i]);
    m = wave_max_f(m);
    if ((threadIdx.x & 63) == 0) sm[threadIdx.x >> 6] = m;
    __syncthreads();
    if (threadIdx.x == 0)
        *slot = enc_f(fmaxf(fmaxf(sm[0], sm[1]), fmaxf(sm[2], sm[3])));
}

// ---------------- activation quant x -> int8 (offset -128) ----------------
__global__ __launch_bounds__(256) void k_quant_act(const float4* __restrict__ in,
                                                   char4* __restrict__ out, long n4,
                                                   const unsigned* __restrict__ slot) {
    float s = fmaxf(dec_f(*slot), EPSQ) / 255.0f;
    long i = (long)blockIdx.x * 256 + threadIdx.x;
    for (; i < n4; i += (long)gridDim.x * 256) {
        float4 v = in[i];
        int a = min(max((int)rintf(v.x / s), 0), 255) - 128;
        int b = min(max((int)rintf(v.y / s), 0), 255) - 128;
        int c = min(max((int)rintf(v.z / s), 0), 255) - 128;
        int d = min(max((int)rintf(v.w / s), 0), 255) - 128;
        char4 cc; cc.x = (char)a; cc.y = (char)b; cc.z = (char)c; cc.w = (char)d;
        out[i] = cc;
    }
}

// ---------------- async global -> LDS, 16B per lane ----------------
__device__ __forceinline__ void gl_lds16(const signed char* g, signed char* l) {
    __builtin_amdgcn_global_load_lds(
        (const __attribute__((address_space(1))) unsigned int*)g,
        (__attribute__((address_space(3))) unsigned int*)l, 16, 0, 0);
}

// ---------------- i8 GEMM, 16x16x64 MFMA, 128x128 tile, BK=64 ---------------
// Pipelined single-barrier double-buffered K-loop (R8-proven fence skeleton):
//   iter it: explicit s_waitcnt vmcnt(0) -> barrier -> stage buf[it+1] ->
//   compute buf[it]. The drain at iter it waits on staging issued at iter
//   it-1, i.e. one full compute phase earlier -> latency hidden. One barrier
//   per iter (reads of buf[x] in compute(it-1) complete before barrier(it),
//   writes to buf[x] at iter it+1... disjoint by parity).
// BK=64 keeps LDS at 2x16KB = 32KB -> 4 blocks/CU (16 waves) for cross-block
// overlap on top of in-loop pipelining (R7/m132 lesson: don't buy BK with
// occupancy). R4-proven 16-row-panel layout: staging 64B-per-row chunks,
// frag reads wave-contiguous 1KB ds_read_b128, zero bank conflicts.
// MODE 0: fp32 store; MODE 1: relu->global max only; MODE 2: relu->u8 quant store.
template<int MODE>
__global__ __launch_bounds__(256, 4) void k_gemm_i8(
    const signed char* __restrict__ A,   // [M][K]
    const signed char* __restrict__ B,   // [N][K]
    const float* __restrict__ s_w,       // [N]
    const int* __restrict__ rowsum,      // [N]
    const float* __restrict__ bias,      // [N]
    const unsigned* __restrict__ act_slot,
    float* __restrict__ Cf,              // MODE 0
    signed char* __restrict__ Cq,        // MODE 2
    unsigned* __restrict__ omax_slot,    // MODE 1: target; MODE 2: source
    int M, int N, long K) {
    __shared__ __align__(16) signed char L[2][16384];   // [buf][A 8KB | B 8KB]
    __shared__ float red[4];

    const int t    = threadIdx.x;
    const int lane = t & 63;
    const int w    = t >> 6;
    const int m0   = blockIdx.y * 128;
    const int n0   = blockIdx.x * 128;
    const int mr   = lane & 15;   // row-in-panel / C-D col-in-16
    const int qq   = lane >> 4;   // k-group / C-D row-quad

    // staging: wave w stages A panels 2w,2w+1 and B panels 2w,2w+1
    const signed char* a0 = A + (long)(m0 + w * 32 + mr) * K + qq * 16;
    const signed char* b0 = B + (long)(n0 + w * 32 + mr) * K + qq * 16;
    const int ad_off = w * 2048 + lane * 16;          // A region [0, 8K)
    const int bd_off = 8192 + w * 2048 + lane * 16;   // B region [8K, 16K)

    const int wrow = (w >> 1) * 64;
    const int wcol = (w & 1) * 64;
    const int a_base = (w >> 1) * 4096 + lane * 16;
    const int b_base = 8192 + (w & 1) * 4096 + lane * 16;

    i32x4 acc[4][4];
    #pragma unroll
    for (int i = 0; i < 4; i++)
        #pragma unroll
        for (int j = 0; j < 4; j++) acc[i][j] = (i32x4){0, 0, 0, 0};

    auto stage = [&](signed char* buf, long k0) {
        gl_lds16(a0 + k0,          buf + ad_off);
        gl_lds16(a0 + k0 + 16 * K, buf + ad_off + 1024);
        gl_lds16(b0 + k0,          buf + bd_off);
        gl_lds16(b0 + k0 + 16 * K, buf + bd_off + 1024);
    };
    auto compute = [&](const signed char* buf) {
        i32x4 af[4], bf[4];
        #pragma unroll
        for (int i = 0; i < 4; i++)
            af[i] = *(const i32x4*)(buf + a_base + i * 1024);
        #pragma unroll
        for (int j = 0; j < 4; j++)
            bf[j] = *(const i32x4*)(buf + b_base + j * 1024);
        #pragma unroll
        for (int i = 0; i < 4; i++)
            #pragma unroll
            for (int j = 0; j < 4; j++)
                acc[i][j] = __builtin_amdgcn_mfma_i32_16x16x64_i8(
                    af[i], bf[j], acc[i][j], 0, 0, 0);
    };

    const int NIT = (int)(K >> 6);
    stage(L[0], 0);

    for (int it = 0; it < NIT; ++it) {
        const int cur = it & 1;
        __builtin_amdgcn_s_waitcnt(0x0F70);   // vmcnt(0): buf[cur] staging landed
                                              // (issued one compute phase ago)
        __syncthreads();                      // all waves' staging visible;
                                              // prior readers of buf[cur^1] done
        if (it + 1 < NIT)
            stage(L[cur ^ 1], (long)(it + 1) * 64);  // drained NEXT iter
        compute(L[cur]);
    }

    // ---- epilogue ----
    const float s_act = fmaxf(dec_f(*act_slot), EPSQ) / 255.0f;

    if (MODE == 1) {
        // max(relu(h)); h = ssc*(v+bint) monotone in integer v per column
        float lmax = 0.0f;
        #pragma unroll
        for (int j = 0; j < 4; j++) {
            int im = -2147483647 - 1;
            #pragma unroll
            for (int i = 0; i < 4; i++)
                #pragma unroll
                for (int r = 0; r < 4; r++) im = max(im, acc[i][j][r]);
            int gn = n0 + wcol + j * 16 + mr;
            float ssc  = s_act * s_w[gn];
            float bint = rintf(bias[gn] / ssc);
            float h = ssc * ((float)(im + 128 * rowsum[gn]) + bint);
            lmax = fmaxf(lmax, h);
        }
        lmax = fmaxf(lmax, 0.0f);
        lmax = wave_max_f(lmax);
        if (lane == 0) red[w] = lmax;
        __syncthreads();
        if (t == 0)   // one atomic per block, staggered over the dispatch
            atomicMax(omax_slot,
                      enc_f(fmaxf(fmaxf(red[0], red[1]), fmaxf(red[2], red[3]))));
        return;
    }

    float s_oq = 1.0f;
    if (MODE == 2) s_oq = fmaxf(dec_f(*omax_slot), EPSQ) / 255.0f;

    #pragma unroll
    for (int j = 0; j < 4; j++) {
        int gn = n0 + wcol + j * 16 + mr;       // C/D col = lane&15
        float ssc  = s_act * s_w[gn];
        float bint = rintf(bias[gn] / ssc);
        int   icor = 128 * rowsum[gn];          // uint8 zero-point correction
        float fq   = (MODE == 2) ? (ssc / s_oq) : 0.0f;
        #pragma unroll
        for (int i = 0; i < 4; i++) {
            #pragma unroll
            for (int r = 0; r < 4; r++) {
                int gm = m0 + wrow + i * 16 + qq * 4 + r;  // C/D row
                float v = (float)(acc[i][j][r] + icor) + bint;
                if (MODE == 0) {
                    Cf[(long)gm * N + gn] = ssc * v;
                } else {
                    int qv = min(max((int)rintf(fq * v), 0), 255) - 128;
                    Cq[(long)gm * N + gn] = (signed char)qv;
                }
            }
        }
    }
}

extern "C" void kernel_launch(void* const* d_in, const int* in_sizes, int n_in,
                              void* d_out, int out_size, void* d_ws, size_t ws_size,
                              hipStream_t stream) {
    const float* x  = (const float*)d_in[0];  // [4,2048,1024]
    const float* w1 = (const float*)d_in[1];  // [4096,1024]
    const float* b1 = (const float*)d_in[2];  // [4096]
    const float* w2 = (const float*)d_in[3];  // [1024,4096]
    const float* b2 = (const float*)d_in[4];  // [1024]
    float* out = (float*)d_out;               // [4,2048,1024] fp32

    const int M = 8192, D = 1024, F = 4096;

    char* ws = (char*)d_ws;
    size_t off = 0;
    unsigned* slots = (unsigned*)ws;               off += 256;  // [0]=max x, [1]=max h
    float* partials = (float*)(ws + off);          off += 2048 * 4;
    signed char* xi  = (signed char*)(ws + off);   off += (size_t)M * D;  // 8 MB
    signed char* w1q = (signed char*)(ws + off);   off += (size_t)F * D;  // 4 MB
    signed char* w2q = (signed char*)(ws + off);   off += (size_t)D * F;  // 4 MB
    float* sw1 = (float*)(ws + off);               off += (size_t)F * 4;
    float* sw2 = (float*)(ws + off);               off += (size_t)D * 4;
    int* rs1   = (int*)(ws + off);                 off += (size_t)F * 4;
    int* rs2   = (int*)(ws + off);                 off += (size_t)D * 4;
    signed char* hq = (signed char*)(ws + off);    off += (size_t)M * F;  // 32 MB

    hipMemsetAsync(slots, 0, 8, stream);  // slots[1]=0 < any encoded real value

    k_prep<<<dim3(2048 + F + D), dim3(256), 0, stream>>>(
        (const float4*)x, (long)M * D / 4, partials,
        w1, w1q, sw1, rs1, w2, w2q, sw2, rs2);
    k_reduce_max<<<dim3(1), dim3(256), 0, stream>>>(partials, 2048, slots + 0);
    k_quant_act<<<dim3(2048), dim3(256), 0, stream>>>((const float4*)x, (char4*)xi,
                                                      (long)M * D / 4, slots + 0);
    // GEMM1 pass 1: max(relu(h)) only
    k_gemm_i8<1><<<dim3(F / 128, M / 128), dim3(256), 0, stream>>>(
        xi, w1q, sw1, rs1, b1, slots + 0, nullptr, nullptr, slots + 1, M, F, (long)D);
    // GEMM1 pass 2: write quantized h (int8, offset -128)
    k_gemm_i8<2><<<dim3(F / 128, M / 128), dim3(256), 0, stream>>>(
        xi, w1q, sw1, rs1, b1, slots + 0, nullptr, hq, slots + 1, M, F, (long)D);
    // GEMM2: fp32 output
    k_gemm_i8<0><<<dim3(D / 128, M / 128), dim3(256), 0, stream>>>(
        hq, w2q, sw2, rs2, b2, slots + 1, out, nullptr, nullptr, M, D, (long)F);

    (void)in_sizes; (void)n_in; (void)out_size; (void)ws_size;
}

// Round 10
// 295.478 us; speedup vs baseline: 1.3540x; 1.0978x over previous
//
#include <hip/hip_runtime.h>
#include <stdint.h>

#define EPSQ 1e-8f

typedef __attribute__((ext_vector_type(4))) int i32x4;

// ---- monotone float<->uint encoding so atomicMax(unsigned) orders floats ----
__device__ __forceinline__ unsigned enc_f(float f) {
    unsigned u = __float_as_uint(f);
    return (u & 0x80000000u) ? ~u : (u | 0x80000000u);
}
__device__ __forceinline__ float dec_f(unsigned u) {
    return (u & 0x80000000u) ? __uint_as_float(u & 0x7fffffffu)
                             : __uint_as_float(~u);
}

__device__ __forceinline__ float wave_max_f(float v) {
    #pragma unroll
    for (int off = 32; off; off >>= 1) v = fmaxf(v, __shfl_xor(v, off));
    return v;
}
__device__ __forceinline__ int wave_sum_i(int v) {
    #pragma unroll
    for (int off = 32; off; off >>= 1) v += __shfl_xor(v, off);
    return v;
}

// ---------------- fused prep: x partial max + per-row quant of w1, w2 -------
// blocks [0,2048): x-max grid-stride -> partials[b] (NO atomics);
// [2048,6144): w1 rows; [6144,7168): w2 rows
__global__ __launch_bounds__(256) void k_prep(
    const float4* __restrict__ x, long n4x, float* __restrict__ partials,
    const float* __restrict__ w1, signed char* __restrict__ w1q,
    float* __restrict__ sw1, int* __restrict__ rs1,
    const float* __restrict__ w2, signed char* __restrict__ w2q,
    float* __restrict__ sw2, int* __restrict__ rs2) {
    __shared__ float sm[4];
    __shared__ int   si[4];
    int b = blockIdx.x;
    int wid = threadIdx.x >> 6;
    if (b < 2048) {
        long i = (long)b * 256 + threadIdx.x;
        float m = -3.4e38f;
        for (; i < n4x; i += 2048L * 256) {
            float4 v = x[i];
            m = fmaxf(fmaxf(m, fmaxf(v.x, v.y)), fmaxf(v.z, v.w));
        }
        m = wave_max_f(m);
        if ((threadIdx.x & 63) == 0) sm[wid] = m;
        __syncthreads();
        if (threadIdx.x == 0)
            partials[b] = fmaxf(fmaxf(sm[0], sm[1]), fmaxf(sm[2], sm[3]));
        return;
    }
    const float* w; signed char* q; float* s_out; int* rs_out; int row, L;
    if (b < 2048 + 4096) { row = b - 2048; w = w1; q = w1q; s_out = sw1; rs_out = rs1; L = 1024; }
    else                 { row = b - 6144; w = w2; q = w2q; s_out = sw2; rs_out = rs2; L = 4096; }

    const float4* wr = (const float4*)(w + (long)row * L);
    int n4 = L >> 2;
    float m = 0.0f;
    for (int i = threadIdx.x; i < n4; i += 256) {
        float4 v = wr[i];
        m = fmaxf(m, fmaxf(fmaxf(fabsf(v.x), fabsf(v.y)),
                           fmaxf(fabsf(v.z), fabsf(v.w))));
    }
    m = wave_max_f(m);
    if ((threadIdx.x & 63) == 0) sm[wid] = m;
    __syncthreads();
    m = fmaxf(fmaxf(sm[0], sm[1]), fmaxf(sm[2], sm[3]));
    float s = fmaxf(m, EPSQ) / 127.0f;   // same fp32 ops as reference

    char4* qr = (char4*)(q + (long)row * L);
    int isum = 0;
    for (int i = threadIdx.x; i < n4; i += 256) {
        float4 v = wr[i];
        int a = min(max((int)rintf(v.x / s), -128), 127);
        int bb = min(max((int)rintf(v.y / s), -128), 127);
        int c = min(max((int)rintf(v.z / s), -128), 127);
        int d = min(max((int)rintf(v.w / s), -128), 127);
        isum += a + bb + c + d;
        char4 cc; cc.x = (char)a; cc.y = (char)bb; cc.z = (char)c; cc.w = (char)d;
        qr[i] = cc;
    }
    isum = wave_sum_i(isum);
    if ((threadIdx.x & 63) == 0) si[wid] = isum;
    __syncthreads();
    if (threadIdx.x == 0) {
        s_out[row]  = s;
        rs_out[row] = si[0] + si[1] + si[2] + si[3];
    }
}

// ---------------- activation quant x -> int8 (offset -128) ------------------
// Also: every block redundantly reduces partials[0..2048) (L2-hot, ~8KB) to
// get s without a separate reduce kernel; block 0 publishes slots[0] (encoded
// max x, read by GEMM epilogues) and zeroes slots[1] (h-max accumulator) --
// both consumed only by later-in-stream dispatches.
__global__ __launch_bounds__(256) void k_quant_act(
    const float4* __restrict__ in, char4* __restrict__ out, long n4,
    const float* __restrict__ partials, unsigned* __restrict__ slots) {
    __shared__ float sm[4];
    float m = -3.4e38f;
    for (int i = threadIdx.x; i < 2048; i += 256) m = fmaxf(m, partials[i]);
    m = wave_max_f(m);
    if ((threadIdx.x & 63) == 0) sm[threadIdx.x >> 6] = m;
    __syncthreads();
    m = fmaxf(fmaxf(sm[0], sm[1]), fmaxf(sm[2], sm[3]));
    if (blockIdx.x == 0 && threadIdx.x == 0) {
        slots[0] = enc_f(m);
        slots[1] = 0u;     // 0 < any encoded real value
    }
    float s = fmaxf(m, EPSQ) / 255.0f;
    long i = (long)blockIdx.x * 256 + threadIdx.x;
    for (; i < n4; i += (long)gridDim.x * 256) {
        float4 v = in[i];
        int a = min(max((int)rintf(v.x / s), 0), 255) - 128;
        int b = min(max((int)rintf(v.y / s), 0), 255) - 128;
        int c = min(max((int)rintf(v.z / s), 0), 255) - 128;
        int d = min(max((int)rintf(v.w / s), 0), 255) - 128;
        char4 cc; cc.x = (char)a; cc.y = (char)b; cc.z = (char)c; cc.w = (char)d;
        out[i] = cc;
    }
}

// ---------------- async global -> LDS, 16B per lane ----------------
__device__ __forceinline__ void gl_lds16(const signed char* g, signed char* l) {
    __builtin_amdgcn_global_load_lds(
        (const __attribute__((address_space(1))) unsigned int*)g,
        (__attribute__((address_space(3))) unsigned int*)l, 16, 0, 0);
}

// ---------------- i8 GEMM, 16x16x64 MFMA, BM x 128 tile, BK=128 -------------
// R6-proven config (best measured): 2-barrier K-loop, 16-row-panel LDS layout,
// 64B-per-row staging chunks, conflict-free wave-contiguous ds_read_b128.
// BM=256/NW=8 for GEMM1 (ops/LDS-byte 170), BM=128/NW=4 for GEMM2.
// MODE 0: fp32 store; MODE 1: relu->global max only; MODE 2: relu->u8 quant store.
template<int MODE, int BM, int NW>
__global__ __launch_bounds__(NW * 64, (MODE == 0 ? 3 : 4)) void k_gemm_i8(
    const signed char* __restrict__ A,   // [M][K]
    const signed char* __restrict__ B,   // [N][K]
    const float* __restrict__ s_w,       // [N]
    const int* __restrict__ rowsum,      // [N]
    const float* __restrict__ bias,      // [N]
    const unsigned* __restrict__ act_slot,
    float* __restrict__ Cf,              // MODE 0
    signed char* __restrict__ Cq,        // MODE 2
    unsigned* __restrict__ omax_slot,    // MODE 1: target; MODE 2: source
    int M, int N, long K) {
    __shared__ __align__(16) signed char Als[BM * 128];
    __shared__ __align__(16) signed char Bls[128 * 128];
    __shared__ float red[NW];

    const int t    = threadIdx.x;
    const int lane = t & 63;
    const int w    = t >> 6;
    const int m0   = blockIdx.y * BM;
    const int n0   = blockIdx.x * 128;
    const int mr   = lane & 15;   // row-in-panel / C-D col-in-16
    const int qq   = lane >> 4;   // k-group / C-D row-quad
    constexpr int PB = 8 / NW;    // B panels per wave

    const signed char* a0 = A + (long)(m0 + w * 32 + mr) * K + qq * 16;
    const signed char* b0 = B + (long)(n0 + w * PB * 16 + mr) * K + qq * 16;
    signed char* ad = Als + w * 4096 + lane * 16;
    signed char* bd = Bls + w * PB * 2048 + lane * 16;

    const int wrow = (w >> 1) * 64;
    const int wcol = (w & 1) * 64;
    const int a_base = (w >> 1) * 8192 + lane * 16;
    const int b_base = (w & 1) * 8192 + lane * 16;

    i32x4 acc[4][4];
    #pragma unroll
    for (int i = 0; i < 4; i++)
        #pragma unroll
        for (int j = 0; j < 4; j++) acc[i][j] = (i32x4){0, 0, 0, 0};

    for (long k0 = 0; k0 < K; k0 += 128) {
        __syncthreads();                    // previous iter's reads done
        gl_lds16(a0 + k0,               ad);
        gl_lds16(a0 + k0 + 64,          ad + 1024);
        gl_lds16(a0 + k0 + 16 * K,      ad + 2048);
        gl_lds16(a0 + k0 + 16 * K + 64, ad + 3072);
        #pragma unroll
        for (int p = 0; p < PB; p++) {
            gl_lds16(b0 + k0 + (long)p * 16 * K,      bd + p * 2048);
            gl_lds16(b0 + k0 + (long)p * 16 * K + 64, bd + p * 2048 + 1024);
        }
        __syncthreads();                    // vmcnt(0) drain: staging visible

        #pragma unroll
        for (int kk = 0; kk < 2; kk++) {
            i32x4 af[4], bf[4];
            #pragma unroll
            for (int i = 0; i < 4; i++)
                af[i] = *(const i32x4*)(Als + a_base + i * 2048 + kk * 1024);
            #pragma unroll
            for (int j = 0; j < 4; j++)
                bf[j] = *(const i32x4*)(Bls + b_base + j * 2048 + kk * 1024);
            #pragma unroll
            for (int i = 0; i < 4; i++)
                #pragma unroll
                for (int j = 0; j < 4; j++)
                    acc[i][j] = __builtin_amdgcn_mfma_i32_16x16x64_i8(
                        af[i], bf[j], acc[i][j], 0, 0, 0);
        }
    }

    // ---- epilogue ----
    const float s_act = fmaxf(dec_f(*act_slot), EPSQ) / 255.0f;

    if (MODE == 1) {
        // max(relu(h)); h = ssc*(v+bint) monotone in integer v per column
        float lmax = 0.0f;
        #pragma unroll
        for (int j = 0; j < 4; j++) {
            int im = -2147483647 - 1;
            #pragma unroll
            for (int i = 0; i < 4; i++)
                #pragma unroll
                for (int r = 0; r < 4; r++) im = max(im, acc[i][j][r]);
            int gn = n0 + wcol + j * 16 + mr;
            float ssc  = s_act * s_w[gn];
            float bint = rintf(bias[gn] / ssc);
            float h = ssc * ((float)(im + 128 * rowsum[gn]) + bint);
            lmax = fmaxf(lmax, h);
        }
        lmax = fmaxf(lmax, 0.0f);
        lmax = wave_max_f(lmax);
        if (lane == 0) red[w] = lmax;
        __syncthreads();
        if (t == 0) {  // one atomic per block, staggered over the dispatch
            float bm = red[0];
            #pragma unroll
            for (int i = 1; i < NW; i++) bm = fmaxf(bm, red[i]);
            atomicMax(omax_slot, enc_f(bm));
        }
        return;
    }

    float s_oq = 1.0f;
    if (MODE == 2) s_oq = fmaxf(dec_f(*omax_slot), EPSQ) / 255.0f;

    #pragma unroll
    for (int j = 0; j < 4; j++) {
        int gn = n0 + wcol + j * 16 + mr;       // C/D col = lane&15
        float ssc  = s_act * s_w[gn];
        float bint = rintf(bias[gn] / ssc);
        int   icor = 128 * rowsum[gn];          // uint8 zero-point correction
        float fq   = (MODE == 2) ? (ssc / s_oq) : 0.0f;
        #pragma unroll
        for (int i = 0; i < 4; i++) {
            #pragma unroll
            for (int r = 0; r < 4; r++) {
                int gm = m0 + wrow + i * 16 + qq * 4 + r;  // C/D row
                float v = (float)(acc[i][j][r] + icor) + bint;
                if (MODE == 0) {
                    Cf[(long)gm * N + gn] = ssc * v;
                } else {
                    int qv = min(max((int)rintf(fq * v), 0), 255) - 128;
                    Cq[(long)gm * N + gn] = (signed char)qv;
                }
            }
        }
    }
}

extern "C" void kernel_launch(void* const* d_in, const int* in_sizes, int n_in,
                              void* d_out, int out_size, void* d_ws, size_t ws_size,
                              hipStream_t stream) {
    const float* x  = (const float*)d_in[0];  // [4,2048,1024]
    const float* w1 = (const float*)d_in[1];  // [4096,1024]
    const float* b1 = (const float*)d_in[2];  // [4096]
    const float* w2 = (const float*)d_in[3];  // [1024,4096]
    const float* b2 = (const float*)d_in[4];  // [1024]
    float* out = (float*)d_out;               // [4,2048,1024] fp32

    const int M = 8192, D = 1024, F = 4096;

    char* ws = (char*)d_ws;
    size_t off = 0;
    unsigned* slots = (unsigned*)ws;               off += 256;  // [0]=max x, [1]=max h
    float* partials = (float*)(ws + off);          off += 2048 * 4;
    signed char* xi  = (signed char*)(ws + off);   off += (size_t)M * D;  // 8 MB
    signed char* w1q = (signed char*)(ws + off);   off += (size_t)F * D;  // 4 MB
    signed char* w2q = (signed char*)(ws + off);   off += (size_t)D * F;  // 4 MB
    float* sw1 = (float*)(ws + off);               off += (size_t)F * 4;
    float* sw2 = (float*)(ws + off);               off += (size_t)D * 4;
    int* rs1   = (int*)(ws + off);                 off += (size_t)F * 4;
    int* rs2   = (int*)(ws + off);                 off += (size_t)D * 4;
    signed char* hq = (signed char*)(ws + off);    off += (size_t)M * F;  // 32 MB

    // 5 graph nodes (was 7): memset folded into k_quant_act (slots[1]=0),
    // reduce folded into k_quant_act (per-block redundant partial reduction).
    k_prep<<<dim3(2048 + F + D), dim3(256), 0, stream>>>(
        (const float4*)x, (long)M * D / 4, partials,
        w1, w1q, sw1, rs1, w2, w2q, sw2, rs2);
    k_quant_act<<<dim3(2048), dim3(256), 0, stream>>>(
        (const float4*)x, (char4*)xi, (long)M * D / 4, partials, slots);
    // GEMM1 pass 1: max(relu(h)) only — 256x128 tile, 512 threads (R6 winner)
    k_gemm_i8<1, 256, 8><<<dim3(F / 128, M / 256), dim3(512), 0, stream>>>(
        xi, w1q, sw1, rs1, b1, slots + 0, nullptr, nullptr, slots + 1, M, F, (long)D);
    // GEMM1 pass 2: write quantized h (int8, offset -128)
    k_gemm_i8<2, 256, 8><<<dim3(F / 128, M / 256), dim3(512), 0, stream>>>(
        xi, w1q, sw1, rs1, b1, slots + 0, nullptr, hq, slots + 1, M, F, (long)D);
    // GEMM2: fp32 output — 128x128 tile, 256 threads (R6 winner)
    k_gemm_i8<0, 128, 4><<<dim3(D / 128, M / 128), dim3(256), 0, stream>>>(
        hq, w2q, sw2, rs2, b2, slots + 1, out, nullptr, nullptr, M, D, (long)F);

    (void)in_sizes; (void)n_in; (void)out_size; (void)ws_size;
}

// Round 11
// 274.912 us; speedup vs baseline: 1.4553x; 1.0748x over previous
//
#include <hip/hip_runtime.h>
#include <stdint.h>

#define EPSQ 1e-8f

typedef __attribute__((ext_vector_type(4))) int i32x4;

// ---- monotone float<->uint encoding so atomicMax(unsigned) orders floats ----
__device__ __forceinline__ unsigned enc_f(float f) {
    unsigned u = __float_as_uint(f);
    return (u & 0x80000000u) ? ~u : (u | 0x80000000u);
}
__device__ __forceinline__ float dec_f(unsigned u) {
    return (u & 0x80000000u) ? __uint_as_float(u & 0x7fffffffu)
                             : __uint_as_float(~u);
}

__device__ __forceinline__ float wave_max_f(float v) {
    #pragma unroll
    for (int off = 32; off; off >>= 1) v = fmaxf(v, __shfl_xor(v, off));
    return v;
}
__device__ __forceinline__ int wave_sum_i(int v) {
    #pragma unroll
    for (int off = 32; off; off >>= 1) v += __shfl_xor(v, off);
    return v;
}

// ---------------- fused prep: x partial max + per-row quant of w1, w2 -------
// blocks [0,2048): x-max grid-stride -> partials[b] (NO atomics);
// [2048,6144): w1 rows; [6144,7168): w2 rows
__global__ __launch_bounds__(256) void k_prep(
    const float4* __restrict__ x, long n4x, float* __restrict__ partials,
    const float* __restrict__ w1, signed char* __restrict__ w1q,
    float* __restrict__ sw1, int* __restrict__ rs1,
    const float* __restrict__ w2, signed char* __restrict__ w2q,
    float* __restrict__ sw2, int* __restrict__ rs2) {
    __shared__ float sm[4];
    __shared__ int   si[4];
    int b = blockIdx.x;
    int wid = threadIdx.x >> 6;
    if (b < 2048) {
        long i = (long)b * 256 + threadIdx.x;
        float m = -3.4e38f;
        for (; i < n4x; i += 2048L * 256) {
            float4 v = x[i];
            m = fmaxf(fmaxf(m, fmaxf(v.x, v.y)), fmaxf(v.z, v.w));
        }
        m = wave_max_f(m);
        if ((threadIdx.x & 63) == 0) sm[wid] = m;
        __syncthreads();
        if (threadIdx.x == 0)
            partials[b] = fmaxf(fmaxf(sm[0], sm[1]), fmaxf(sm[2], sm[3]));
        return;
    }
    const float* w; signed char* q; float* s_out; int* rs_out; int row, L;
    if (b < 2048 + 4096) { row = b - 2048; w = w1; q = w1q; s_out = sw1; rs_out = rs1; L = 1024; }
    else                 { row = b - 6144; w = w2; q = w2q; s_out = sw2; rs_out = rs2; L = 4096; }

    const float4* wr = (const float4*)(w + (long)row * L);
    int n4 = L >> 2;
    float m = 0.0f;
    for (int i = threadIdx.x; i < n4; i += 256) {
        float4 v = wr[i];
        m = fmaxf(m, fmaxf(fmaxf(fabsf(v.x), fabsf(v.y)),
                           fmaxf(fabsf(v.z), fabsf(v.w))));
    }
    m = wave_max_f(m);
    if ((threadIdx.x & 63) == 0) sm[wid] = m;
    __syncthreads();
    m = fmaxf(fmaxf(sm[0], sm[1]), fmaxf(sm[2], sm[3]));
    float s = fmaxf(m, EPSQ) / 127.0f;   // same fp32 ops as reference

    char4* qr = (char4*)(q + (long)row * L);
    int isum = 0;
    for (int i = threadIdx.x; i < n4; i += 256) {
        float4 v = wr[i];
        int a = min(max((int)rintf(v.x / s), -128), 127);
        int bb = min(max((int)rintf(v.y / s), -128), 127);
        int c = min(max((int)rintf(v.z / s), -128), 127);
        int d = min(max((int)rintf(v.w / s), -128), 127);
        isum += a + bb + c + d;
        char4 cc; cc.x = (char)a; cc.y = (char)bb; cc.z = (char)c; cc.w = (char)d;
        qr[i] = cc;
    }
    isum = wave_sum_i(isum);
    if ((threadIdx.x & 63) == 0) si[wid] = isum;
    __syncthreads();
    if (threadIdx.x == 0) {
        s_out[row]  = s;
        rs_out[row] = si[0] + si[1] + si[2] + si[3];
    }
}

// ---------------- activation quant x -> int8 (offset -128) ------------------
// Every block redundantly reduces partials (L2-hot 8KB); block 0 publishes
// slots[0] (encoded max x) and zeroes slots[1] (h-max accumulator).
__global__ __launch_bounds__(256) void k_quant_act(
    const float4* __restrict__ in, char4* __restrict__ out, long n4,
    const float* __restrict__ partials, unsigned* __restrict__ slots) {
    __shared__ float sm[4];
    float m = -3.4e38f;
    for (int i = threadIdx.x; i < 2048; i += 256) m = fmaxf(m, partials[i]);
    m = wave_max_f(m);
    if ((threadIdx.x & 63) == 0) sm[threadIdx.x >> 6] = m;
    __syncthreads();
    m = fmaxf(fmaxf(sm[0], sm[1]), fmaxf(sm[2], sm[3]));
    if (blockIdx.x == 0 && threadIdx.x == 0) {
        slots[0] = enc_f(m);
        slots[1] = 0u;     // 0 < any encoded real value
    }
    float s = fmaxf(m, EPSQ) / 255.0f;
    long i = (long)blockIdx.x * 256 + threadIdx.x;
    for (; i < n4; i += (long)gridDim.x * 256) {
        float4 v = in[i];
        int a = min(max((int)rintf(v.x / s), 0), 255) - 128;
        int b = min(max((int)rintf(v.y / s), 0), 255) - 128;
        int c = min(max((int)rintf(v.z / s), 0), 255) - 128;
        int d = min(max((int)rintf(v.w / s), 0), 255) - 128;
        char4 cc; cc.x = (char)a; cc.y = (char)b; cc.z = (char)c; cc.w = (char)d;
        out[i] = cc;
    }
}

// -------- requant: u16 (per-block scale) -> uint8 global units, offset -128 --
// element e: m = e>>12, f = e&4095 (F=4096); GEMM1 block = (m>>8, f>>7),
// sblk idx = (m>>8)*32 + (f>>7). q = clip(round(u * blk/(65535*s_h)),0,255)-128
__global__ __launch_bounds__(256) void k_requant(
    const ushort4* __restrict__ h16, char4* __restrict__ hq,
    const float* __restrict__ sblk, const unsigned* __restrict__ slots, long n4) {
    float s_h = fmaxf(dec_f(slots[1]), EPSQ) / 255.0f;
    float inv = 1.0f / (65535.0f * s_h);
    long i = (long)blockIdx.x * 256 + threadIdx.x;
    for (; i < n4; i += (long)gridDim.x * 256) {
        long e = i << 2;
        int m = (int)(e >> 12);
        int f = (int)(e & 4095);
        float fq = sblk[(m >> 8) * 32 + (f >> 7)] * inv;
        ushort4 u = h16[i];
        char4 cc;
        cc.x = (char)(min(max((int)rintf(u.x * fq), 0), 255) - 128);
        cc.y = (char)(min(max((int)rintf(u.y * fq), 0), 255) - 128);
        cc.z = (char)(min(max((int)rintf(u.z * fq), 0), 255) - 128);
        cc.w = (char)(min(max((int)rintf(u.w * fq), 0), 255) - 128);
        hq[i] = cc;
    }
}

// ---------------- async global -> LDS, 16B per lane ----------------
__device__ __forceinline__ void gl_lds16(const signed char* g, signed char* l) {
    __builtin_amdgcn_global_load_lds(
        (const __attribute__((address_space(1))) unsigned int*)g,
        (__attribute__((address_space(3))) unsigned int*)l, 16, 0, 0);
}

// ---------------- i8 GEMM, 16x16x64 MFMA, BM x 128 tile, BK=128 -------------
// R6/R10-proven config: 2-barrier K-loop, 16-row-panel LDS layout, 64B-per-row
// staging chunks, conflict-free wave-contiguous ds_read_b128.
// MODE 0: fp32 store (GEMM2, BM=128/NW=4).
// MODE 3: single-pass GEMM1 (BM=256/NW=8): relu -> block max -> u16 store with
//         per-block scale; sblk + global atomicMax(h max).
template<int MODE, int BM, int NW>
__global__ __launch_bounds__(NW * 64, (MODE == 0 ? 3 : 4)) void k_gemm_i8(
    const signed char* __restrict__ A,   // [M][K]
    const signed char* __restrict__ B,   // [N][K]
    const float* __restrict__ s_w,       // [N]
    const int* __restrict__ rowsum,      // [N]
    const float* __restrict__ bias,      // [N]
    const unsigned* __restrict__ act_slot,
    float* __restrict__ Cf,              // MODE 0
    unsigned short* __restrict__ H16,    // MODE 3
    float* __restrict__ sblk,            // MODE 3
    unsigned* __restrict__ omax_slot,    // MODE 3 target
    int M, int N, long K) {
    __shared__ __align__(16) signed char Als[BM * 128];
    __shared__ __align__(16) signed char Bls[128 * 128];
    __shared__ float red[NW];

    const int t    = threadIdx.x;
    const int lane = t & 63;
    const int w    = t >> 6;
    const int m0   = blockIdx.y * BM;
    const int n0   = blockIdx.x * 128;
    const int mr   = lane & 15;   // row-in-panel / C-D col-in-16
    const int qq   = lane >> 4;   // k-group / C-D row-quad
    constexpr int PB = 8 / NW;    // B panels per wave

    const signed char* a0 = A + (long)(m0 + w * 32 + mr) * K + qq * 16;
    const signed char* b0 = B + (long)(n0 + w * PB * 16 + mr) * K + qq * 16;
    signed char* ad = Als + w * 4096 + lane * 16;
    signed char* bd = Bls + w * PB * 2048 + lane * 16;

    const int wrow = (w >> 1) * 64;
    const int wcol = (w & 1) * 64;
    const int a_base = (w >> 1) * 8192 + lane * 16;
    const int b_base = (w & 1) * 8192 + lane * 16;

    i32x4 acc[4][4];
    #pragma unroll
    for (int i = 0; i < 4; i++)
        #pragma unroll
        for (int j = 0; j < 4; j++) acc[i][j] = (i32x4){0, 0, 0, 0};

    for (long k0 = 0; k0 < K; k0 += 128) {
        __syncthreads();                    // previous iter's reads done
        gl_lds16(a0 + k0,               ad);
        gl_lds16(a0 + k0 + 64,          ad + 1024);
        gl_lds16(a0 + k0 + 16 * K,      ad + 2048);
        gl_lds16(a0 + k0 + 16 * K + 64, ad + 3072);
        #pragma unroll
        for (int p = 0; p < PB; p++) {
            gl_lds16(b0 + k0 + (long)p * 16 * K,      bd + p * 2048);
            gl_lds16(b0 + k0 + (long)p * 16 * K + 64, bd + p * 2048 + 1024);
        }
        __syncthreads();                    // vmcnt(0) drain: staging visible

        #pragma unroll
        for (int kk = 0; kk < 2; kk++) {
            i32x4 af[4], bf[4];
            #pragma unroll
            for (int i = 0; i < 4; i++)
                af[i] = *(const i32x4*)(Als + a_base + i * 2048 + kk * 1024);
            #pragma unroll
            for (int j = 0; j < 4; j++)
                bf[j] = *(const i32x4*)(Bls + b_base + j * 2048 + kk * 1024);
            #pragma unroll
            for (int i = 0; i < 4; i++)
                #pragma unroll
                for (int j = 0; j < 4; j++)
                    acc[i][j] = __builtin_amdgcn_mfma_i32_16x16x64_i8(
                        af[i], bf[j], acc[i][j], 0, 0, 0);
        }
    }

    // ---- epilogue ----
    const float s_act = fmaxf(dec_f(*act_slot), EPSQ) / 255.0f;

    if (MODE == 3) {
        float sscv[4], bintv[4]; int icorv[4];
        float lmax = 0.0f;
        #pragma unroll
        for (int j = 0; j < 4; j++) {
            int gn = n0 + wcol + j * 16 + mr;
            float ssc  = s_act * s_w[gn];
            float bint = rintf(bias[gn] / ssc);
            int   icor = 128 * rowsum[gn];
            sscv[j] = ssc; bintv[j] = bint; icorv[j] = icor;
            int im = -2147483647 - 1;   // h monotone in integer acc per column
            #pragma unroll
            for (int i = 0; i < 4; i++)
                #pragma unroll
                for (int r = 0; r < 4; r++) im = max(im, acc[i][j][r]);
            lmax = fmaxf(lmax, ssc * ((float)(im + icor) + bint));
        }
        lmax = fmaxf(lmax, 0.0f);
        lmax = wave_max_f(lmax);
        if (lane == 0) red[w] = lmax;
        __syncthreads();
        float bm = red[0];
        #pragma unroll
        for (int i = 1; i < NW; i++) bm = fmaxf(bm, red[i]);
        if (t == 0) {
            sblk[blockIdx.y * gridDim.x + blockIdx.x] = bm;
            atomicMax(omax_slot, enc_f(bm));
        }
        float inv = 65535.0f / fmaxf(bm, EPSQ);
        #pragma unroll
        for (int j = 0; j < 4; j++) {
            int gn = n0 + wcol + j * 16 + mr;
            #pragma unroll
            for (int i = 0; i < 4; i++) {
                #pragma unroll
                for (int r = 0; r < 4; r++) {
                    int gm = m0 + wrow + i * 16 + qq * 4 + r;
                    float h = fmaxf(
                        sscv[j] * ((float)(acc[i][j][r] + icorv[j]) + bintv[j]),
                        0.0f);
                    int u = min((int)rintf(h * inv), 65535);
                    H16[(long)gm * N + gn] = (unsigned short)u;
                }
            }
        }
        return;
    }

    // MODE 0: fp32 output
    #pragma unroll
    for (int j = 0; j < 4; j++) {
        int gn = n0 + wcol + j * 16 + mr;       // C/D col = lane&15
        float ssc  = s_act * s_w[gn];
        float bint = rintf(bias[gn] / ssc);
        int   icor = 128 * rowsum[gn];          // uint8 zero-point correction
        #pragma unroll
        for (int i = 0; i < 4; i++) {
            #pragma unroll
            for (int r = 0; r < 4; r++) {
                int gm = m0 + wrow + i * 16 + qq * 4 + r;  // C/D row
                Cf[(long)gm * N + gn] =
                    ssc * ((float)(acc[i][j][r] + icor) + bint);
            }
        }
    }
}

extern "C" void kernel_launch(void* const* d_in, const int* in_sizes, int n_in,
                              void* d_out, int out_size, void* d_ws, size_t ws_size,
                              hipStream_t stream) {
    const float* x  = (const float*)d_in[0];  // [4,2048,1024]
    const float* w1 = (const float*)d_in[1];  // [4096,1024]
    const float* b1 = (const float*)d_in[2];  // [4096]
    const float* w2 = (const float*)d_in[3];  // [1024,4096]
    const float* b2 = (const float*)d_in[4];  // [1024]
    float* out = (float*)d_out;               // [4,2048,1024] fp32

    const int M = 8192, D = 1024, F = 4096;

    char* ws = (char*)d_ws;
    size_t off = 0;
    unsigned* slots = (unsigned*)ws;               off += 256;  // [0]=max x, [1]=max h
    float* partials = (float*)(ws + off);          off += 2048 * 4;
    signed char* xi  = (signed char*)(ws + off);   off += (size_t)M * D;      // 8 MB
    signed char* w1q = (signed char*)(ws + off);   off += (size_t)F * D;      // 4 MB
    signed char* w2q = (signed char*)(ws + off);   off += (size_t)D * F;      // 4 MB
    float* sw1 = (float*)(ws + off);               off += (size_t)F * 4;
    float* sw2 = (float*)(ws + off);               off += (size_t)D * 4;
    int* rs1   = (int*)(ws + off);                 off += (size_t)F * 4;
    int* rs2   = (int*)(ws + off);                 off += (size_t)D * 4;
    signed char* hq = (signed char*)(ws + off);    off += (size_t)M * F;      // 32 MB
    unsigned short* h16 = (unsigned short*)(ws + off); off += (size_t)M * F * 2; // 64 MB
    float* sblk = (float*)(ws + off);              off += 1024 * 4;

    k_prep<<<dim3(2048 + F + D), dim3(256), 0, stream>>>(
        (const float4*)x, (long)M * D / 4, partials,
        w1, w1q, sw1, rs1, w2, w2q, sw2, rs2);
    k_quant_act<<<dim3(2048), dim3(256), 0, stream>>>(
        (const float4*)x, (char4*)xi, (long)M * D / 4, partials, slots);
    // GEMM1 single pass: relu -> block-scaled u16 + block/global max
    k_gemm_i8<3, 256, 8><<<dim3(F / 128, M / 256), dim3(512), 0, stream>>>(
        xi, w1q, sw1, rs1, b1, slots + 0, nullptr, h16, sblk, slots + 1,
        M, F, (long)D);
    // u16 -> final uint8 units (offset -128)
    k_requant<<<dim3(2048), dim3(256), 0, stream>>>(
        (const ushort4*)h16, (char4*)hq, sblk, slots, (long)M * F / 4);
    // GEMM2: fp32 output
    k_gemm_i8<0, 128, 4><<<dim3(D / 128, M / 128), dim3(256), 0, stream>>>(
        hq, w2q, sw2, rs2, b2, slots + 1, out, nullptr, nullptr, nullptr,
        M, D, (long)F);

    (void)in_sizes; (void)n_in; (void)out_size; (void)ws_size;
}